// Round 1
// baseline (1641.786 us; speedup 1.0000x reference)
//
#include <hip/hip_runtime.h>
#include <hip/hip_bf16.h>

#define B_ 4
#define L_ 2048
#define D_ 1024
#define H_ 16

typedef __attribute__((ext_vector_type(4))) float f32x4;
typedef __attribute__((ext_vector_type(8))) _Float16 half8;
typedef __attribute__((ext_vector_type(4))) _Float16 half4;

#define MFMA16(a, b, c) __builtin_amdgcn_mfma_f32_16x16x32_f16(a, b, c, 0, 0, 0)

// async global->LDS, 16B per lane; LDS dest must be wave-uniform-base + lane*16
__device__ __forceinline__ void gld_lds16(const void* g, void* l) {
    __builtin_amdgcn_global_load_lds(
        (__attribute__((address_space(1))) const void*)(g),
        (__attribute__((address_space(3))) void*)(l),
        16, 0, 0);
}

// ---------------------------------------------------------------- cast fp32->fp16
__global__ __launch_bounds__(256) void cast_kernel(const float* __restrict__ in,
                                                   _Float16* __restrict__ out, int n) {
    int i = (blockIdx.x * 256 + threadIdx.x) * 4;
    if (i >= n) return;
    float4 v = *(const float4*)(in + i);
    half4 o;
    o.x = (_Float16)v.x; o.y = (_Float16)v.y; o.z = (_Float16)v.z; o.w = (_Float16)v.w;
    *(half4*)(out + i) = o;
}

// ---------------------------------------------------------------- GEMM C = A @ W^T + bias
// A: [M,K] fp16 row-major; W: [N,K] fp16 row-major (B^T pattern, both K-contiguous)
// 128x128 tile, BK=64, 4 waves each 64x64 (4x4 MFMA 16x16x32), global_load_lds staging.
template <bool OUT_HALF>
__global__ __launch_bounds__(256) void gemm_bt(const _Float16* __restrict__ A,
                                               const _Float16* __restrict__ W,
                                               const float* __restrict__ bias,
                                               _Float16* __restrict__ outh,
                                               float* __restrict__ outf,
                                               int M, int N, int K) {
    __shared__ _Float16 sA[128 * 64];
    __shared__ _Float16 sB[128 * 64];
    const int tid = threadIdx.x, lane = tid & 63, w = tid >> 6;
    const int m0 = blockIdx.y * 128, n0 = blockIdx.x * 128;
    const int wr = (w >> 1) * 64, wc = (w & 1) * 64;
    const int lanelo = lane & 15, kq = (lane >> 4) * 8;

    f32x4 acc[4][4] = {};

    for (int k0 = 0; k0 < K; k0 += 64) {
        __syncthreads();
        for (int it = 0; it < 4; ++it) {
            int idx = it * 256 + tid;
            int r = idx >> 3, c = (idx & 7) * 8;
            gld_lds16(A + (size_t)(m0 + r) * K + k0 + c, sA + idx * 8);
            gld_lds16(W + (size_t)(n0 + r) * K + k0 + c, sB + idx * 8);
        }
        __syncthreads();
        for (int ks = 0; ks < 2; ++ks) {
            half8 af[4], bf[4];
            for (int t = 0; t < 4; ++t)
                af[t] = *(const half8*)(sA + (wr + t * 16 + lanelo) * 64 + ks * 32 + kq);
            for (int t = 0; t < 4; ++t)
                bf[t] = *(const half8*)(sB + (wc + t * 16 + lanelo) * 64 + ks * 32 + kq);
            for (int tm = 0; tm < 4; ++tm)
                for (int tn = 0; tn < 4; ++tn)
                    acc[tm][tn] = MFMA16(af[tm], bf[tn], acc[tm][tn]);
        }
    }
    // epilogue: C/D layout col=lane&15, row=(lane>>4)*4+reg
    const int rq = (lane >> 4) * 4;
    for (int tm = 0; tm < 4; ++tm) {
        int row = m0 + wr + tm * 16 + rq;
        for (int tn = 0; tn < 4; ++tn) {
            int col = n0 + wc + tn * 16 + lanelo;
            float bb = bias[col];
            for (int r = 0; r < 4; ++r) {
                float v = acc[tm][tn][r] + bb;
                if (OUT_HALF)
                    outh[(size_t)(row + r) * N + col] = (_Float16)v;
                else
                    outf[(size_t)(row + r) * N + col] = v;
            }
        }
    }
}

// ---------------------------------------------------------------- transpose V: vh[b,m,h*64+d] -> vt[b,h,d,m]
__global__ __launch_bounds__(256) void transpose_v(const ushort* __restrict__ vh,
                                                   ushort* __restrict__ vt) {
    __shared__ ushort tile[64 * 72];
    const int tid = threadIdx.x;
    const int mb = blockIdx.x, h = blockIdx.y, b = blockIdx.z;
    const ushort* src = vh + ((size_t)(b * L_ + mb * 64)) * D_ + h * 64;
    for (int it = 0; it < 2; ++it) {
        int idx = it * 256 + tid, r = idx >> 3, c = (idx & 7) * 8;
        *(uint4*)(tile + r * 72 + c) = *(const uint4*)(src + (size_t)r * D_ + c);
    }
    __syncthreads();
    ushort* dst = vt + ((size_t)(b * H_ + h) * 64) * (size_t)L_ + mb * 64;
    for (int it = 0; it < 2; ++it) {
        int idx = it * 256 + tid;
        int d = idx & 63, c = (idx >> 6) * 8;
        union { ushort u[8]; uint4 v; } pk;
        for (int j = 0; j < 8; ++j) pk.u[j] = tile[(c + j) * 72 + d];
        *(uint4*)(dst + (size_t)d * L_ + c) = pk.v;
    }
}

// ---------------------------------------------------------------- fused attention
// One workgroup per (b, h, 64 q-rows). Pass 1: online row max/sumexp over K tiles.
// Pass 2: recompute S, write normalized P (fp32 -> d_out), P->LDS fp16, PV accumulate.
__global__ __launch_bounds__(256) void attn_kernel(const _Float16* __restrict__ qh,
                                                   const _Float16* __restrict__ kh,
                                                   const _Float16* __restrict__ vt,
                                                   float* __restrict__ attn_out,
                                                   _Float16* __restrict__ ctx) {
    __shared__ _Float16 sQ[64 * 64];
    __shared__ _Float16 sK[64 * 64];
    __shared__ _Float16 sV[64 * 64];
    __shared__ _Float16 sP[64 * 72];  // padded stride: P C-layout -> A-layout round trip

    const int tid = threadIdx.x, lane = tid & 63, w = tid >> 6;
    const int lb = blockIdx.x, h = blockIdx.y, b = blockIdx.z;
    const int l0 = lb * 64;
    const int lanelo = lane & 15, kq = (lane >> 4) * 8, rq = (lane >> 4) * 4;

    // stage Q tile (64 rows x 64 d), lives for whole kernel
    const _Float16* qbase = qh + ((size_t)(b * L_ + l0)) * D_ + h * 64;
    for (int it = 0; it < 2; ++it) {
        int idx = it * 256 + tid, r = idx >> 3, c = (idx & 7) * 8;
        gld_lds16(qbase + (size_t)r * D_ + c, sQ + idx * 8);
    }
    __syncthreads();
    half8 aq[2];
    aq[0] = *(const half8*)(sQ + (w * 16 + lanelo) * 64 + kq);
    aq[1] = *(const half8*)(sQ + (w * 16 + lanelo) * 64 + 32 + kq);

    float m_run[4], s_run[4];
    for (int r = 0; r < 4; ++r) { m_run[r] = -1e30f; s_run[r] = 0.f; }

    const _Float16* kbase = kh + ((size_t)b * L_) * D_ + h * 64;
    const int rowg0 = l0 + w * 16 + rq;  // global l of reg r is rowg0 + r

    // ---------------- pass 1: stats only
    for (int mt = 0; mt < 32; ++mt) {
        __syncthreads();
        for (int it = 0; it < 2; ++it) {
            int idx = it * 256 + tid, r = idx >> 3, c = (idx & 7) * 8;
            gld_lds16(kbase + (size_t)(mt * 64 + r) * D_ + c, sK + idx * 8);
        }
        __syncthreads();
        f32x4 accs[4] = {};
        for (int ks = 0; ks < 2; ++ks)
            for (int tn = 0; tn < 4; ++tn) {
                half8 bk = *(const half8*)(sK + (tn * 16 + lanelo) * 64 + ks * 32 + kq);
                accs[tn] = MFMA16(aq[ks], bk, accs[tn]);
            }
        const int colg0 = mt * 64 + lanelo;
        float tmax[4] = {-1e30f, -1e30f, -1e30f, -1e30f};
        for (int tn = 0; tn < 4; ++tn)
            for (int r = 0; r < 4; ++r) {
                float v = accs[tn][r] * 0.125f;
                if (rowg0 + r == colg0 + tn * 16) v = -1e30f;  // diagonal mask
                accs[tn][r] = v;
                tmax[r] = fmaxf(tmax[r], v);
            }
        // rows live in 16-lane groups (same lane>>4): xor-reduce within 16
        for (int off = 8; off >= 1; off >>= 1)
            for (int r = 0; r < 4; ++r)
                tmax[r] = fmaxf(tmax[r], __shfl_xor(tmax[r], off));
        for (int r = 0; r < 4; ++r) {
            float mnew = fmaxf(m_run[r], tmax[r]);
            float ts = 0.f;
            for (int tn = 0; tn < 4; ++tn) ts += __expf(accs[tn][r] - mnew);
            for (int off = 8; off >= 1; off >>= 1) ts += __shfl_xor(ts, off);
            s_run[r] = s_run[r] * __expf(m_run[r] - mnew) + ts;
            m_run[r] = mnew;
        }
    }
    float rcp_s[4];
    for (int r = 0; r < 4; ++r) rcp_s[r] = 1.f / s_run[r];

    // ---------------- pass 2: P write + PV
    const _Float16* vbase = vt + ((size_t)(b * H_ + h) * 64) * (size_t)L_;
    float* abase = attn_out + ((size_t)(h * B_ + b) * L_) * (size_t)L_;
    f32x4 acco[4] = {};
    for (int mt = 0; mt < 32; ++mt) {
        __syncthreads();
        for (int it = 0; it < 2; ++it) {
            int idx = it * 256 + tid, r = idx >> 3, c = (idx & 7) * 8;
            gld_lds16(kbase + (size_t)(mt * 64 + r) * D_ + c, sK + idx * 8);
            gld_lds16(vbase + (size_t)r * L_ + mt * 64 + c, sV + idx * 8);
        }
        __syncthreads();
        f32x4 accs[4] = {};
        for (int ks = 0; ks < 2; ++ks)
            for (int tn = 0; tn < 4; ++tn) {
                half8 bk = *(const half8*)(sK + (tn * 16 + lanelo) * 64 + ks * 32 + kq);
                accs[tn] = MFMA16(aq[ks], bk, accs[tn]);
            }
        const int colg0 = mt * 64 + lanelo;
        for (int tn = 0; tn < 4; ++tn)
            for (int r = 0; r < 4; ++r) {
                float v = accs[tn][r] * 0.125f;
                if (rowg0 + r == colg0 + tn * 16) v = -1e30f;
                float p = __expf(v - m_run[r]) * rcp_s[r];
                abase[(size_t)(rowg0 + r) * L_ + colg0 + tn * 16] = p;
                sP[(w * 16 + rq + r) * 72 + tn * 16 + lanelo] = (_Float16)p;
            }
        __syncthreads();  // sP visible before A-frag reads
        for (int ks = 0; ks < 2; ++ks) {
            half8 ap = *(const half8*)(sP + (w * 16 + lanelo) * 72 + ks * 32 + kq);
            for (int tn = 0; tn < 4; ++tn) {
                half8 bv = *(const half8*)(sV + (tn * 16 + lanelo) * 64 + ks * 32 + kq);
                acco[tn] = MFMA16(ap, bv, acco[tn]);
            }
        }
    }
    // epilogue: O -> ctx (fp16), coalesced via sP staging
    __syncthreads();
    for (int tn = 0; tn < 4; ++tn)
        for (int r = 0; r < 4; ++r)
            sP[(w * 16 + rq + r) * 72 + tn * 16 + lanelo] = (_Float16)(acco[tn][r]);
    __syncthreads();
    _Float16* cdst = ctx + ((size_t)(b * L_ + l0)) * D_ + h * 64;
    {
        int row = tid >> 2, c = (tid & 3) * 16;
        uint4 v0 = *(const uint4*)(sP + row * 72 + c);
        uint4 v1 = *(const uint4*)(sP + row * 72 + c + 8);
        *(uint4*)(cdst + (size_t)row * D_ + c) = v0;
        *(uint4*)(cdst + (size_t)row * D_ + c + 8) = v1;
    }
}

// ---------------------------------------------------------------- residual + LayerNorm (in-place on d_out)
__global__ __launch_bounds__(256) void ln_kernel(float* __restrict__ y,
                                                 const float* __restrict__ resid,
                                                 const float* __restrict__ gamma,
                                                 const float* __restrict__ beta) {
    const int row = blockIdx.x, tid = threadIdx.x;
    const int col = tid * 4;
    float4 yv = *(const float4*)(y + (size_t)row * 1024 + col);
    float4 rv = *(const float4*)(resid + (size_t)row * 1024 + col);
    float4 x;
    x.x = yv.x + rv.x; x.y = yv.y + rv.y; x.z = yv.z + rv.z; x.w = yv.w + rv.w;
    float s = x.x + x.y + x.z + x.w;
    float ss = x.x * x.x + x.y * x.y + x.z * x.z + x.w * x.w;
    for (int off = 32; off >= 1; off >>= 1) {
        s += __shfl_down(s, off);
        ss += __shfl_down(ss, off);
    }
    __shared__ float as_[4], ass_[4];
    if ((tid & 63) == 0) { as_[tid >> 6] = s; ass_[tid >> 6] = ss; }
    __syncthreads();
    s = as_[0] + as_[1] + as_[2] + as_[3];
    ss = ass_[0] + ass_[1] + ass_[2] + ass_[3];
    float mean = s * (1.f / 1024.f);
    float var = ss * (1.f / 1024.f) - mean * mean;
    float rstd = rsqrtf(var + 1e-5f);
    float4 g = *(const float4*)(gamma + col);
    float4 bt = *(const float4*)(beta + col);
    float4 o;
    o.x = (x.x - mean) * rstd * g.x + bt.x;
    o.y = (x.y - mean) * rstd * g.y + bt.y;
    o.z = (x.z - mean) * rstd * g.z + bt.z;
    o.w = (x.w - mean) * rstd * g.w + bt.w;
    *(float4*)(y + (size_t)row * 1024 + col) = o;
}

// ----------------------------------------------------------------
extern "C" void kernel_launch(void* const* d_in, const int* in_sizes, int n_in,
                              void* d_out, int out_size, void* d_ws, size_t ws_size,
                              hipStream_t stream) {
    const float* q     = (const float*)d_in[0];
    const float* k     = (const float*)d_in[1];
    const float* v     = (const float*)d_in[2];
    const float* Wq    = (const float*)d_in[3];
    const float* bq    = (const float*)d_in[4];
    const float* Wk    = (const float*)d_in[5];
    const float* bk    = (const float*)d_in[6];
    const float* Wv    = (const float*)d_in[7];
    const float* bv    = (const float*)d_in[8];
    const float* Wo    = (const float*)d_in[9];
    const float* bo    = (const float*)d_in[10];
    const float* gamma = (const float*)d_in[11];
    const float* beta  = (const float*)d_in[12];

    char* ws = (char*)d_ws;
    const size_t MB = 1ull << 20;
    // ws layout (88 MB), with aliased reuse in dependency order:
    _Float16* qf16 = (_Float16*)(ws + 0);        // 16 MB; dead after Q-proj -> reused as vh
    _Float16* kf16 = (_Float16*)(ws + 16 * MB);  // 16 MB; dead after K-proj -> reused as vt
    _Float16* vf16 = (_Float16*)(ws + 32 * MB);  // 16 MB; dead after V-proj -> reused as ctx
    _Float16* qh   = (_Float16*)(ws + 48 * MB);  // 16 MB
    _Float16* kh   = (_Float16*)(ws + 64 * MB);  // 16 MB
    _Float16* Wqh  = (_Float16*)(ws + 80 * MB);  // 2 MB
    _Float16* Wkh  = (_Float16*)(ws + 82 * MB);
    _Float16* Wvh  = (_Float16*)(ws + 84 * MB);
    _Float16* Woh  = (_Float16*)(ws + 86 * MB);
    _Float16* vh   = qf16;
    _Float16* vt   = kf16;
    _Float16* ctx  = vf16;

    const int nQ = B_ * L_ * D_;      // 8388608
    const int nW = 1024 * 1024;

    cast_kernel<<<nQ / 1024, 256, 0, stream>>>(q, qf16, nQ);
    cast_kernel<<<nQ / 1024, 256, 0, stream>>>(k, kf16, nQ);
    cast_kernel<<<nQ / 1024, 256, 0, stream>>>(v, vf16, nQ);
    cast_kernel<<<nW / 1024, 256, 0, stream>>>(Wq, Wqh, nW);
    cast_kernel<<<nW / 1024, 256, 0, stream>>>(Wk, Wkh, nW);
    cast_kernel<<<nW / 1024, 256, 0, stream>>>(Wv, Wvh, nW);
    cast_kernel<<<nW / 1024, 256, 0, stream>>>(Wo, Woh, nW);

    dim3 gg(1024 / 128, 8192 / 128);  // (N/128, M/128)
    gemm_bt<true><<<gg, 256, 0, stream>>>(qf16, Wqh, bq, qh, nullptr, 8192, 1024, 1024);
    gemm_bt<true><<<gg, 256, 0, stream>>>(kf16, Wkh, bk, kh, nullptr, 8192, 1024, 1024);
    gemm_bt<true><<<gg, 256, 0, stream>>>(vf16, Wvh, bv, vh, nullptr, 8192, 1024, 1024);

    transpose_v<<<dim3(L_ / 64, H_, B_), 256, 0, stream>>>((const ushort*)vh, (ushort*)vt);

    float* attn_out = (float*)d_out + (size_t)B_ * L_ * D_;
    attn_kernel<<<dim3(L_ / 64, H_, B_), 256, 0, stream>>>(qh, kh, vt, attn_out, ctx);

    // out-projection straight into d_out (fp32), then LN in place
    gemm_bt<false><<<gg, 256, 0, stream>>>(ctx, Woh, bo, nullptr, (float*)d_out, 8192, 1024, 1024);
    ln_kernel<<<B_ * L_, 256, 0, stream>>>((float*)d_out, q, gamma, beta);
}